// Round 1
// baseline (256.877 us; speedup 1.0000x reference)
//
#include <hip/hip_runtime.h>

#define M_Q 50000
#define N_S 50000
#define H_N 32
#define K_P 15
#define C_IN 128
#define C_OUT 128

// One query point per 128-thread block.
// Phase 1 (lanes 0..31): gather neighbor coords, compute 15 kernel weights each,
//   build bitmasks of active neighbors / active kernel points (exact zero-skip).
// Phase 2 (thread = input channel c): accumulate wf[k][c] over active neighbors.
// Phase 3 (thread = output channel d): acc += wf[k][c] * W[k][c][d] over active k.
template <typename IT>
__global__ __launch_bounds__(128, 8) void kpconv_kernel(
    const float* __restrict__ q_pts,
    const float* __restrict__ s_pts,
    const float* __restrict__ s_feats,
    const IT* __restrict__ neighb_inds,
    const float* __restrict__ kernel_points,
    const float* __restrict__ weights,
    float* __restrict__ out)
{
    __shared__ float s_kp[K_P * 3];
    __shared__ float s_w[K_P][H_N];   // weights w[k][h]
    __shared__ int s_idx[H_N];
    __shared__ unsigned s_hmask;      // bit h: neighbor h has any nonzero weight
    __shared__ unsigned s_kmask;      // bit k: kernel point k has any nonzero weight
    __shared__ float s_wf[K_P][C_IN]; // weighted features

    const int m = blockIdx.x;
    const int tid = threadIdx.x;

    if (tid < K_P * 3) s_kp[tid] = kernel_points[tid];
    if (tid == 0) { s_hmask = 0u; s_kmask = 0u; }
    __syncthreads();

    // ---- phase 1: geometry + weights ----
    if (tid < H_N) {
        long long idx = (long long)neighb_inds[(size_t)m * H_N + tid];
        const float qx = q_pts[m * 3 + 0];
        const float qy = q_pts[m * 3 + 1];
        const float qz = q_pts[m * 3 + 2];
        float rx, ry, rz;
        int idx32;
        if ((unsigned long long)idx < (unsigned long long)N_S) {
            idx32 = (int)idx;
            rx = s_pts[idx32 * 3 + 0] - qx;
            ry = s_pts[idx32 * 3 + 1] - qy;
            rz = s_pts[idx32 * 3 + 2] - qz;
        } else {
            // matches reference: padded far-away point -> zero influence, zero feats
            idx32 = 0;
            rx = ry = rz = 1.0e6f;
        }
        s_idx[tid] = idx32;

        unsigned kmask = 0u;
        #pragma unroll
        for (int k = 0; k < K_P; ++k) {
            const float dx = rx - s_kp[k * 3 + 0];
            const float dy = ry - s_kp[k * 3 + 1];
            const float dz = rz - s_kp[k * 3 + 2];
            const float d2 = dx * dx + dy * dy + dz * dz;
            const float w = fmaxf(1.0f - sqrtf(d2), 0.0f); // SIGMA = 1.0
            s_w[k][tid] = w;
            if (w > 0.0f) kmask |= (1u << k);
        }
        if (kmask) {
            atomicOr(&s_hmask, 1u << tid);
            atomicOr(&s_kmask, kmask);
        }
    }
    __syncthreads();

    const unsigned hmask = s_hmask;
    const unsigned kmask = s_kmask;

    // ---- phase 2: weighted feature accumulation (thread = channel c) ----
    float wf[K_P];
    #pragma unroll
    for (int k = 0; k < K_P; ++k) wf[k] = 0.0f;
    {
        const int c = tid;
        unsigned hm = hmask;
        while (hm) {
            const int h = __builtin_ctz(hm);
            hm &= hm - 1;
            const float f = s_feats[(size_t)s_idx[h] * C_IN + c];
            #pragma unroll
            for (int k = 0; k < K_P; ++k)
                wf[k] = fmaf(s_w[k][h], f, wf[k]);
        }
        #pragma unroll
        for (int k = 0; k < K_P; ++k) s_wf[k][tid] = wf[k];
    }
    __syncthreads();

    // ---- phase 3: out[m][d] = sum_{active k} sum_c wf[k][c] * W[k][c][d] ----
    float acc = 0.0f;
    {
        const int d = tid;
        unsigned km = kmask;
        while (km) {
            const int k = __builtin_ctz(km);
            km &= km - 1;
            const float* Wk = weights + (size_t)k * C_IN * C_OUT + d;
            #pragma unroll 8
            for (int c = 0; c < C_IN; ++c)
                acc = fmaf(s_wf[k][c], Wk[(size_t)c * C_OUT], acc);
        }
    }
    out[(size_t)m * C_OUT + tid] = acc;
}

extern "C" void kernel_launch(void* const* d_in, const int* in_sizes, int n_in,
                              void* d_out, int out_size, void* d_ws, size_t ws_size,
                              hipStream_t stream) {
    const float* q_pts         = (const float*)d_in[0];
    const float* s_pts         = (const float*)d_in[1];
    const float* s_feats       = (const float*)d_in[2];
    const float* kernel_points = (const float*)d_in[4];
    const float* weights       = (const float*)d_in[5];
    float* out = (float*)d_out;

    dim3 grid(M_Q), block(128);
    if (in_sizes[3] == 2 * M_Q * H_N) {
        // indices stored as int64
        const long long* inds = (const long long*)d_in[3];
        kpconv_kernel<long long><<<grid, block, 0, stream>>>(
            q_pts, s_pts, s_feats, inds, kernel_points, weights, out);
    } else {
        const int* inds = (const int*)d_in[3];
        kpconv_kernel<int><<<grid, block, 0, stream>>>(
            q_pts, s_pts, s_feats, inds, kernel_points, weights, out);
    }
}

// Round 2
// 206.627 us; speedup vs baseline: 1.2432x; 1.2432x over previous
//
#include <hip/hip_runtime.h>

#define M_Q 50000
#define N_S 50000
#define H_N 32
#define K_P 15
#define C_IN 128
#define C_OUT 128
#define QB 32      // queries per block
#define AP 136     // padded A row length in bf16 elems (128 + 8 to break bank stride)

typedef __attribute__((ext_vector_type(8))) short s8v;   // 8 bf16 (4 VGPRs) MFMA A/B frag
typedef __attribute__((ext_vector_type(4))) float f4v;   // MFMA C/D frag
typedef __attribute__((ext_vector_type(4))) float fl4;

static __device__ __forceinline__ unsigned f2bf_bits(float x) {
    // round-to-nearest-even fp32 -> bf16 bits (inputs are finite)
    union { float f; unsigned u; } v; v.f = x;
    return (v.u + 0x7fffu + ((v.u >> 16) & 1u)) >> 16;
}

// ---- pre-pass: W[k][c][d] fp32  ->  Wt[k][d][c] bf16 (B-operand friendly) ----
__global__ __launch_bounds__(256) void wcvt_kernel(const float* __restrict__ W,
                                                   unsigned short* __restrict__ Wt) {
    int i = blockIdx.x * 256 + threadIdx.x;
    if (i >= K_P * C_IN * C_OUT) return;
    int c = i & 127, d = (i >> 7) & 127, k = i >> 14;
    Wt[i] = (unsigned short)f2bf_bits(W[((size_t)k * 128 + c) * 128 + d]);
}

// ---- main: 32 queries per block, per-k MFMA GEMM with exact zero-skip A build ----
template <typename IT>
__global__ __launch_bounds__(256, 4) void kpconv_mfma(
    const float* __restrict__ q_pts,
    const float* __restrict__ s_pts,
    const float* __restrict__ s_feats,
    const IT* __restrict__ inds,
    const float* __restrict__ kernel_points,
    const unsigned short* __restrict__ Wt,   // bf16 bits, [K][D][C]
    float* __restrict__ out)
{
    __shared__ float s_kp[K_P * 3];
    __shared__ float s_q[QB * 3];
    __shared__ float s_r[QB][H_N][3];        // neighbor - query relative pos
    __shared__ int s_idx[QB][H_N];
    __shared__ unsigned s_hm[K_P][QB];       // active-h bitmask per (k, q)
    __shared__ unsigned short s_A[QB][AP];   // A_k tile, bf16 bits

    const int t = threadIdx.x;
    const int qbase = blockIdx.x * QB;

    if (t < K_P * 3) s_kp[t] = kernel_points[t];
    for (int i = t; i < K_P * QB; i += 256) ((unsigned*)s_hm)[i] = 0u;
    if (t < QB * 3) {
        int g = qbase * 3 + t;
        s_q[t] = (g < M_Q * 3) ? q_pts[g] : 0.0f;
    }
    __syncthreads();

    // ---- phase 1: geometry, 32q x 32h tasks, 4 per thread ----
    #pragma unroll
    for (int it = 0; it < 4; ++it) {
        const int task = t + it * 256;
        const int q = task >> 5, h = task & 31;
        const int qg = qbase + q;
        if (qg < M_Q) {
            long long idx = (long long)inds[(size_t)qg * H_N + h];
            float rx, ry, rz; int i32;
            if ((unsigned long long)idx < (unsigned long long)N_S) {
                i32 = (int)idx;
                rx = s_pts[i32 * 3 + 0] - s_q[q * 3 + 0];
                ry = s_pts[i32 * 3 + 1] - s_q[q * 3 + 1];
                rz = s_pts[i32 * 3 + 2] - s_q[q * 3 + 2];
            } else { i32 = 0; rx = ry = rz = 1.0e6f; }
            s_idx[q][h] = i32;
            s_r[q][h][0] = rx; s_r[q][h][1] = ry; s_r[q][h][2] = rz;
            #pragma unroll
            for (int k = 0; k < K_P; ++k) {
                const float dx = rx - s_kp[k * 3 + 0];
                const float dy = ry - s_kp[k * 3 + 1];
                const float dz = rz - s_kp[k * 3 + 2];
                const float d2 = dx * dx + dy * dy + dz * dz;
                if (d2 < 1.0f)  // w = 1 - sqrt(d2) > 0  <=>  d2 < 1
                    atomicOr(&s_hm[k][q], 1u << h);
            }
        }
    }
    __syncthreads();

    const int wave = t >> 6, lane = t & 63;
    const int quad = lane >> 4, l15 = lane & 15;
    const int qs = t >> 3, sub = t & 7, c0 = sub * 16;  // A-build: 8 threads/query, 16 c each

    const f4v zf = {0.0f, 0.0f, 0.0f, 0.0f};
    f4v acc[2][2];
    acc[0][0] = zf; acc[0][1] = zf; acc[1][0] = zf; acc[1][1] = zf;

    for (int k = 0; k < K_P; ++k) {
        // ---- build A_k tile (bf16) with exact zero-skip ----
        float v[16];
        #pragma unroll
        for (int j = 0; j < 16; ++j) v[j] = 0.0f;
        unsigned hm = s_hm[k][qs];
        const float kx = s_kp[k * 3 + 0], ky = s_kp[k * 3 + 1], kz = s_kp[k * 3 + 2];
        while (hm) {
            const int h = __builtin_ctz(hm); hm &= hm - 1;
            const float dx = s_r[qs][h][0] - kx;
            const float dy = s_r[qs][h][1] - ky;
            const float dz = s_r[qs][h][2] - kz;
            const float w = fmaxf(1.0f - sqrtf(dx * dx + dy * dy + dz * dz), 0.0f);
            const fl4* fp = (const fl4*)(s_feats + (size_t)s_idx[qs][h] * C_IN + c0);
            #pragma unroll
            for (int j4 = 0; j4 < 4; ++j4) {
                const fl4 f = fp[j4];
                v[j4 * 4 + 0] = fmaf(w, f.x, v[j4 * 4 + 0]);
                v[j4 * 4 + 1] = fmaf(w, f.y, v[j4 * 4 + 1]);
                v[j4 * 4 + 2] = fmaf(w, f.z, v[j4 * 4 + 2]);
                v[j4 * 4 + 3] = fmaf(w, f.w, v[j4 * 4 + 3]);
            }
        }
        #pragma unroll
        for (int j2 = 0; j2 < 8; ++j2) {
            const unsigned lo = f2bf_bits(v[2 * j2 + 0]);
            const unsigned hi = f2bf_bits(v[2 * j2 + 1]);
            *(unsigned*)&s_A[qs][c0 + 2 * j2] = lo | (hi << 16);
        }
        __syncthreads();

        // ---- MFMA: out_tile += A_k (32x128) * Wt_k^T (128x128) ----
        const unsigned short* Wk = Wt + (size_t)k * C_IN * C_OUT;
        #pragma unroll
        for (int kk = 0; kk < 4; ++kk) {
            const int coff = kk * 32 + quad * 8;
            const s8v a0 = *(const s8v*)&s_A[l15][coff];
            const s8v a1 = *(const s8v*)&s_A[16 + l15][coff];
            const s8v b0 = *(const s8v*)(Wk + (size_t)(wave * 32 + l15) * C_IN + coff);
            const s8v b1 = *(const s8v*)(Wk + (size_t)(wave * 32 + 16 + l15) * C_IN + coff);
            acc[0][0] = __builtin_amdgcn_mfma_f32_16x16x32_bf16(a0, b0, acc[0][0], 0, 0, 0);
            acc[1][0] = __builtin_amdgcn_mfma_f32_16x16x32_bf16(a1, b0, acc[1][0], 0, 0, 0);
            acc[0][1] = __builtin_amdgcn_mfma_f32_16x16x32_bf16(a0, b1, acc[0][1], 0, 0, 0);
            acc[1][1] = __builtin_amdgcn_mfma_f32_16x16x32_bf16(a1, b1, acc[1][1], 0, 0, 0);
        }
        __syncthreads();
    }

    // ---- epilogue: C/D layout col=lane&15, row=(lane>>4)*4+reg ----
    #pragma unroll
    for (int mt = 0; mt < 2; ++mt) {
        #pragma unroll
        for (int n2 = 0; n2 < 2; ++n2) {
            #pragma unroll
            for (int r = 0; r < 4; ++r) {
                const int q = qbase + mt * 16 + quad * 4 + r;
                if (q < M_Q)
                    out[(size_t)q * C_OUT + wave * 32 + n2 * 16 + l15] = acc[mt][n2][r];
            }
        }
    }
}

// ---- fallback (V1) for tiny workspaces ----
template <typename IT>
__global__ __launch_bounds__(128, 8) void kpconv_v1(
    const float* __restrict__ q_pts, const float* __restrict__ s_pts,
    const float* __restrict__ s_feats, const IT* __restrict__ neighb_inds,
    const float* __restrict__ kernel_points, const float* __restrict__ weights,
    float* __restrict__ out)
{
    __shared__ float s_kp[K_P * 3];
    __shared__ float s_w[K_P][H_N];
    __shared__ int s_idx[H_N];
    __shared__ unsigned s_hmask, s_kmask;
    __shared__ float s_wf[K_P][C_IN];
    const int m = blockIdx.x, tid = threadIdx.x;
    if (tid < K_P * 3) s_kp[tid] = kernel_points[tid];
    if (tid == 0) { s_hmask = 0u; s_kmask = 0u; }
    __syncthreads();
    if (tid < H_N) {
        long long idx = (long long)neighb_inds[(size_t)m * H_N + tid];
        const float qx = q_pts[m * 3], qy = q_pts[m * 3 + 1], qz = q_pts[m * 3 + 2];
        float rx, ry, rz; int idx32;
        if ((unsigned long long)idx < (unsigned long long)N_S) {
            idx32 = (int)idx;
            rx = s_pts[idx32 * 3] - qx; ry = s_pts[idx32 * 3 + 1] - qy; rz = s_pts[idx32 * 3 + 2] - qz;
        } else { idx32 = 0; rx = ry = rz = 1.0e6f; }
        s_idx[tid] = idx32;
        unsigned kmask = 0u;
        #pragma unroll
        for (int k = 0; k < K_P; ++k) {
            const float dx = rx - s_kp[k * 3], dy = ry - s_kp[k * 3 + 1], dz = rz - s_kp[k * 3 + 2];
            const float w = fmaxf(1.0f - sqrtf(dx * dx + dy * dy + dz * dz), 0.0f);
            s_w[k][tid] = w;
            if (w > 0.0f) kmask |= (1u << k);
        }
        if (kmask) { atomicOr(&s_hmask, 1u << tid); atomicOr(&s_kmask, kmask); }
    }
    __syncthreads();
    const unsigned hmask = s_hmask, kmask = s_kmask;
    float wf[K_P];
    #pragma unroll
    for (int k = 0; k < K_P; ++k) wf[k] = 0.0f;
    unsigned hmv = hmask;
    while (hmv) {
        const int h = __builtin_ctz(hmv); hmv &= hmv - 1;
        const float f = s_feats[(size_t)s_idx[h] * C_IN + tid];
        #pragma unroll
        for (int k = 0; k < K_P; ++k) wf[k] = fmaf(s_w[k][h], f, wf[k]);
    }
    #pragma unroll
    for (int k = 0; k < K_P; ++k) s_wf[k][tid] = wf[k];
    __syncthreads();
    float a = 0.0f;
    unsigned km = kmask;
    while (km) {
        const int k = __builtin_ctz(km); km &= km - 1;
        const float* Wk = weights + (size_t)k * C_IN * C_OUT + tid;
        #pragma unroll 8
        for (int c = 0; c < C_IN; ++c) a = fmaf(s_wf[k][c], Wk[(size_t)c * C_OUT], a);
    }
    out[(size_t)m * C_OUT + tid] = a;
}

extern "C" void kernel_launch(void* const* d_in, const int* in_sizes, int n_in,
                              void* d_out, int out_size, void* d_ws, size_t ws_size,
                              hipStream_t stream) {
    const float* q_pts         = (const float*)d_in[0];
    const float* s_pts         = (const float*)d_in[1];
    const float* s_feats       = (const float*)d_in[2];
    const float* kernel_points = (const float*)d_in[4];
    const float* weights       = (const float*)d_in[5];
    float* out = (float*)d_out;
    const bool i64 = (in_sizes[3] == 2 * M_Q * H_N);
    const size_t wt_bytes = (size_t)K_P * C_IN * C_OUT * sizeof(unsigned short);

    if (ws_size >= wt_bytes) {
        unsigned short* Wt = (unsigned short*)d_ws;
        wcvt_kernel<<<(K_P * C_IN * C_OUT + 255) / 256, 256, 0, stream>>>(weights, Wt);
        dim3 grid((M_Q + QB - 1) / QB), block(256);
        if (i64)
            kpconv_mfma<long long><<<grid, block, 0, stream>>>(
                q_pts, s_pts, s_feats, (const long long*)d_in[3], kernel_points, Wt, out);
        else
            kpconv_mfma<int><<<grid, block, 0, stream>>>(
                q_pts, s_pts, s_feats, (const int*)d_in[3], kernel_points, Wt, out);
    } else {
        dim3 grid(M_Q), block(128);
        if (i64)
            kpconv_v1<long long><<<grid, block, 0, stream>>>(
                q_pts, s_pts, s_feats, (const long long*)d_in[3], kernel_points, weights, out);
        else
            kpconv_v1<int><<<grid, block, 0, stream>>>(
                q_pts, s_pts, s_feats, (const int*)d_in[3], kernel_points, weights, out);
    }
}